// Round 10
// baseline (2365.323 us; speedup 1.0000x reference)
//
#include <hip/hip_runtime.h>
#include <hip/hip_bf16.h>
#include <cstdint>
#include <cstddef>

using hb = __hip_bfloat16;
typedef __bf16 bf16x8 __attribute__((ext_vector_type(8)));
typedef float f32x4 __attribute__((ext_vector_type(4)));
typedef const __attribute__((address_space(1))) void* gptr_t;
typedef __attribute__((address_space(3))) void* lptr_t;

namespace {
constexpr int L_ = 4, V_ = 32000, D_ = 1024, H_ = 16, DFF_ = 4096, HD_ = 64;
constexpr int B_ = 2, T_ = 1024;
constexpr int BT = B_ * T_;  // 2048 rows
constexpr int PSTR = 56;     // P-tile LDS row stride (elems): 112B, 16B-aligned
constexpr int MTILES = BT / 128;  // 16 M-tiles for 128-row GEMMs
}

// ---------------- merged weight cast f32 -> bf16 (1 dispatch for all 5) --------
__device__ __forceinline__ void cast_range(const float* __restrict__ in,
                                           hb* __restrict__ out, int n4,
                                           int base, int stride) {
  for (int i = base; i < n4; i += stride) {
    float4 v = reinterpret_cast<const float4*>(in)[i];
    union { hb h[4]; ushort4 u; } t;
    t.h[0] = __float2bfloat16(v.x);
    t.h[1] = __float2bfloat16(v.y);
    t.h[2] = __float2bfloat16(v.z);
    t.h[3] = __float2bfloat16(v.w);
    reinterpret_cast<ushort4*>(out)[i] = t.u;
  }
}

__global__ __launch_bounds__(256) void k_cast5(
    const float* s0, hb* d0, int n0, const float* s1, hb* d1, int n1,
    const float* s2, hb* d2, int n2, const float* s3, hb* d3, int n3,
    const float* s4, hb* d4, int n4) {
  const int base = blockIdx.x * 256 + threadIdx.x;
  const int stride = gridDim.x * 256;
  cast_range(s0, d0, n0, base, stride);
  cast_range(s1, d1, n1, base, stride);
  cast_range(s2, d2, n2, base, stride);
  cast_range(s3, d3, n3, base, stride);
  cast_range(s4, d4, n4, base, stride);
}

// ---------------- fused embedding + layer-0 ln1 ----------------
// x = wte[idx] + wpe (fp32, kept as residual); out = LN(x) in bf16.
__global__ __launch_bounds__(256) void k_embed_ln(const int* __restrict__ idx,
                                                  const float* __restrict__ wte,
                                                  const float* __restrict__ wpe,
                                                  const float* __restrict__ w,
                                                  const float* __restrict__ b,
                                                  float* __restrict__ x,
                                                  hb* __restrict__ out) {
  const int row = blockIdx.x;
  const int tid = threadIdx.x;
  const int t = row & (T_ - 1);
  const int tok = idx[row];
  const float4 a = reinterpret_cast<const float4*>(wte + (size_t)tok * D_)[tid];
  const float4 p = reinterpret_cast<const float4*>(wpe + (size_t)t * D_)[tid];
  const float4 v = {a.x + p.x, a.y + p.y, a.z + p.z, a.w + p.w};
  reinterpret_cast<float4*>(x + (size_t)row * D_)[tid] = v;
  float s = v.x + v.y + v.z + v.w;
  float ss = v.x * v.x + v.y * v.y + v.z * v.z + v.w * v.w;
#pragma unroll
  for (int o = 32; o; o >>= 1) { s += __shfl_xor(s, o); ss += __shfl_xor(ss, o); }
  __shared__ float rs[4], rss[4];
  const int wid = tid >> 6;
  if ((tid & 63) == 0) { rs[wid] = s; rss[wid] = ss; }
  __syncthreads();
  s = rs[0] + rs[1] + rs[2] + rs[3];
  ss = rss[0] + rss[1] + rss[2] + rss[3];
  const float mu = s * (1.f / D_);
  const float var = ss * (1.f / D_) - mu * mu;
  const float rstd = rsqrtf(var + 1e-5f);
  const float4 wv = reinterpret_cast<const float4*>(w)[tid];
  const float4 bv = reinterpret_cast<const float4*>(b)[tid];
  union { hb h[4]; ushort4 u; } o2;
  o2.h[0] = __float2bfloat16((v.x - mu) * rstd * wv.x + bv.x);
  o2.h[1] = __float2bfloat16((v.y - mu) * rstd * wv.y + bv.y);
  o2.h[2] = __float2bfloat16((v.z - mu) * rstd * wv.z + bv.z);
  o2.h[3] = __float2bfloat16((v.w - mu) * rstd * wv.w + bv.w);
  reinterpret_cast<ushort4*>(out + (size_t)row * D_)[tid] = o2.u;
}

// ---------------- layernorm: fp32 in -> bf16 out ----------------
__global__ __launch_bounds__(256) void k_ln(const float* __restrict__ x,
                                            const float* __restrict__ w,
                                            const float* __restrict__ b,
                                            hb* __restrict__ out) {
  const int row = blockIdx.x;
  const int tid = threadIdx.x;
  const float4 v = reinterpret_cast<const float4*>(x + (size_t)row * D_)[tid];
  float s = v.x + v.y + v.z + v.w;
  float ss = v.x * v.x + v.y * v.y + v.z * v.z + v.w * v.w;
#pragma unroll
  for (int o = 32; o; o >>= 1) { s += __shfl_xor(s, o); ss += __shfl_xor(ss, o); }
  __shared__ float rs[4], rss[4];
  const int wid = tid >> 6;
  if ((tid & 63) == 0) { rs[wid] = s; rss[wid] = ss; }
  __syncthreads();
  s = rs[0] + rs[1] + rs[2] + rs[3];
  ss = rss[0] + rss[1] + rss[2] + rss[3];
  const float mu = s * (1.f / D_);
  const float var = ss * (1.f / D_) - mu * mu;
  const float rstd = rsqrtf(var + 1e-5f);
  const float4 wv = reinterpret_cast<const float4*>(w)[tid];
  const float4 bv = reinterpret_cast<const float4*>(b)[tid];
  union { hb h[4]; ushort4 u; } t;
  t.h[0] = __float2bfloat16((v.x - mu) * rstd * wv.x + bv.x);
  t.h[1] = __float2bfloat16((v.y - mu) * rstd * wv.y + bv.y);
  t.h[2] = __float2bfloat16((v.z - mu) * rstd * wv.z + bv.z);
  t.h[3] = __float2bfloat16((v.w - mu) * rstd * wv.w + bv.w);
  reinterpret_cast<ushort4*>(out + (size_t)row * D_)[tid] = t.u;
}

// ---------------- V transpose: qkv[b][t][2D+h*64+d] -> vt[bh][d][t] ----------------
__global__ __launch_bounds__(256) void k_vtrans(const hb* __restrict__ qkv,
                                                hb* __restrict__ vt) {
  // grid: (B*H, T/64)
  __shared__ __align__(16) hb tile[64][66];
  const int bh = blockIdx.x;
  const int b = bh >> 4, h = bh & (H_ - 1);
  const int t0 = blockIdx.y * 64;
  const int tid = threadIdx.x;
  const int tl = tid >> 2, dc = (tid & 3) * 16;
  const hb* src = qkv + ((size_t)(b * T_ + t0 + tl) * 3 * D_) + 2 * D_ + h * HD_ + dc;
  *reinterpret_cast<bf16x8*>(&tile[tl][dc]) = *reinterpret_cast<const bf16x8*>(src);
  *reinterpret_cast<bf16x8*>(&tile[tl][dc + 8]) = *reinterpret_cast<const bf16x8*>(src + 8);
  __syncthreads();
  const int d = tid & 63, tj = tid >> 6;
  hb o[16];
#pragma unroll
  for (int j = 0; j < 16; ++j) o[j] = tile[tj * 16 + j][d];
  bf16x8* dst = reinterpret_cast<bf16x8*>(vt + ((size_t)bh * HD_ + d) * T_ + t0 + tj * 16);
  dst[0] = *reinterpret_cast<bf16x8*>(&o[0]);
  dst[1] = *reinterpret_cast<bf16x8*>(&o[8]);
}

// ---------------- flash attention: wave per 16-query tile, MFMA ----------------
__global__ __launch_bounds__(256) void k_attn(const hb* __restrict__ qkv,
                                              const hb* __restrict__ vt,
                                              hb* __restrict__ y) {
  const int lane = threadIdx.x & 63;
  const int wid = threadIdx.x >> 6;
  const int gw = blockIdx.x * 4 + wid;     // global wave = (bh, qtile)
  const int qt = 63 - (gw & 63);           // heavy tiles first
  const int bh = gw >> 6;
  const int h = bh & (H_ - 1), b = bh >> 4;
  const int q0 = qt * 16;
  const int lr = lane & 15, g = lane >> 4;

  __shared__ __align__(16) hb plds[4][16 * PSTR];
  hb* pw = plds[wid];

  const size_t qrow = ((size_t)(b * T_ + q0 + lr) * 3 * D_) + (size_t)h * HD_;
  const bf16x8 qa0 = *reinterpret_cast<const bf16x8*>(qkv + qrow + g * 8);
  const bf16x8 qa1 = *reinterpret_cast<const bf16x8*>(qkv + qrow + 32 + g * 8);

  const f32x4 z = {0.f, 0.f, 0.f, 0.f};
  float m[4] = {-1e30f, -1e30f, -1e30f, -1e30f};
  float lsum[4] = {0.f, 0.f, 0.f, 0.f};
  f32x4 o[4];
#pragma unroll
  for (int i = 0; i < 4; ++i) o[i] = z;

  const int nkv = (q0 + 47) >> 5;  // ceil((q0+16)/32) tiles of 32 keys
  for (int kt = 0; kt < nkv; ++kt) {
    const int kv0 = kt * 32;
    f32x4 s[2];
#pragma unroll
    for (int nt = 0; nt < 2; ++nt) {
      const size_t krow =
          ((size_t)(b * T_ + kv0 + nt * 16 + lr) * 3 * D_) + D_ + (size_t)h * HD_;
      const bf16x8 kb0 = *reinterpret_cast<const bf16x8*>(qkv + krow + g * 8);
      const bf16x8 kb1 = *reinterpret_cast<const bf16x8*>(qkv + krow + 32 + g * 8);
      f32x4 acc = z;
      acc = __builtin_amdgcn_mfma_f32_16x16x32_bf16(qa0, kb0, acc, 0, 0, 0);
      acc = __builtin_amdgcn_mfma_f32_16x16x32_bf16(qa1, kb1, acc, 0, 0, 0);
      s[nt] = acc;
    }
    // C layout: col = lane&15 (kv), row = g*4+r (q)   [verified m89]
#pragma unroll
    for (int r = 0; r < 4; ++r) {
      const int qg = q0 + g * 4 + r;
      const float s0 = (kv0 + lr <= qg) ? s[0][r] * 0.125f : -1e30f;
      const float s1 = (kv0 + 16 + lr <= qg) ? s[1][r] * 0.125f : -1e30f;
      float rmax = fmaxf(s0, s1);
#pragma unroll
      for (int off = 1; off < 16; off <<= 1) rmax = fmaxf(rmax, __shfl_xor(rmax, off));
      const float mn = fmaxf(m[r], rmax);
      const float c = __expf(m[r] - mn);
      m[r] = mn;
      const float p0 = __expf(s0 - mn);
      const float p1 = __expf(s1 - mn);
      float ps = p0 + p1;
#pragma unroll
      for (int off = 1; off < 16; off <<= 1) ps += __shfl_xor(ps, off);
      lsum[r] = lsum[r] * c + ps;
#pragma unroll
      for (int dt = 0; dt < 4; ++dt) o[dt][r] *= c;
      pw[(g * 4 + r) * PSTR + lr] = __float2bfloat16(p0);
      pw[(g * 4 + r) * PSTR + 16 + lr] = __float2bfloat16(p1);
    }
    // P A-frag: row=lane&15 (q), k=(lane>>4)*8 (kv)
    const bf16x8 pa = *reinterpret_cast<const bf16x8*>(&pw[lr * PSTR + g * 8]);
#pragma unroll
    for (int dt = 0; dt < 4; ++dt) {
      const bf16x8 vb = *reinterpret_cast<const bf16x8*>(
          vt + ((size_t)bh * HD_ + dt * 16 + lr) * T_ + kv0 + g * 8);
      o[dt] = __builtin_amdgcn_mfma_f32_16x16x32_bf16(pa, vb, o[dt], 0, 0, 0);
    }
  }
#pragma unroll
  for (int dt = 0; dt < 4; ++dt) {
#pragma unroll
    for (int r = 0; r < 4; ++r) {
      const size_t oo =
          ((size_t)(b * T_ + q0 + g * 4 + r) * D_) + h * HD_ + dt * 16 + lr;
      y[oo] = __float2bfloat16(o[dt][r] / lsum[r]);
    }
  }
}

// ---------------- layer GEMM (128-row tiles, counted-vmcnt dbuf) ----------------
template <int EPI, bool OBF, int BN>
__global__ __launch_bounds__(256) void gemm_bt(const hb* __restrict__ A,
                                               const hb* __restrict__ Bw,
                                               const float* __restrict__ bias,
                                               const float* resid,
                                               void* outv, int M, int N, int K) {
  constexpr int WMR = (BN == 128) ? 4 : 2;  // 16-row fragments per wave
  __shared__ __align__(16) hb As[2][128 * 32];
  __shared__ __align__(16) hb Bs[2][BN * 32];
  const int tid = threadIdx.x, lane = tid & 63, wid = tid >> 6;

  const int nwg = gridDim.x;
  const int d = blockIdx.x;
  const int wg = (d & 7) * (nwg >> 3) + (d >> 3);
  const int m0 = (wg & (MTILES - 1)) * 128;
  const int n0 = (wg / MTILES) * BN;

  const int wr = (BN == 128) ? (wid >> 1) : wid;
  const int wc = (BN == 128) ? (wid & 1) : 0;

  f32x4 acc[WMR][4];
  const f32x4 z = {0.f, 0.f, 0.f, 0.f};
#pragma unroll
  for (int i = 0; i < WMR; ++i)
#pragma unroll
    for (int j = 0; j < 4; ++j) acc[i][j] = z;

  const int e0 = tid * 8;
  auto stage = [&](int buf, int k0) {
#pragma unroll
    for (int r = 0; r < 2; ++r) {
      const int e = e0 + r * 2048;
      const int row = e >> 5, col = e & 31;
      __builtin_amdgcn_global_load_lds(
          (gptr_t)(A + (size_t)(m0 + row) * K + k0 + col), (lptr_t)(&As[buf][e]), 16, 0, 0);
    }
#pragma unroll
    for (int r = 0; r < BN / 64; ++r) {
      const int e = e0 + r * 2048;
      const int row = e >> 5, col = e & 31;
      __builtin_amdgcn_global_load_lds(
          (gptr_t)(Bw + (size_t)(n0 + row) * K + k0 + col), (lptr_t)(&Bs[buf][e]), 16, 0, 0);
    }
  };

  stage(0, 0);
  stage(1, 32);

  const int nt = K >> 5;
  const int lr = lane & 15, lk = (lane >> 4) * 8;
  for (int t = 0; t < nt; ++t) {
    const int cur = t & 1;
    if (t + 1 < nt) {
      if constexpr (BN == 128)
        asm volatile("s_waitcnt vmcnt(4)" ::: "memory");
      else
        asm volatile("s_waitcnt vmcnt(3)" ::: "memory");
    } else {
      asm volatile("s_waitcnt vmcnt(0)" ::: "memory");
    }
    asm volatile("s_barrier" ::: "memory");  // all waves: buf cur resident

    bf16x8 af[WMR], bfr[4];
#pragma unroll
    for (int i = 0; i < WMR; ++i)
      af[i] = *reinterpret_cast<const bf16x8*>(
          &As[cur][(wr * (WMR * 16) + i * 16 + lr) * 32 + lk]);
#pragma unroll
    for (int j = 0; j < 4; ++j)
      bfr[j] = *reinterpret_cast<const bf16x8*>(
          &Bs[cur][(wc * 64 + j * 16 + lr) * 32 + lk]);
#pragma unroll
    for (int i = 0; i < WMR; ++i)
#pragma unroll
      for (int j = 0; j < 4; ++j)
        acc[i][j] = __builtin_amdgcn_mfma_f32_16x16x32_bf16(af[i], bfr[j], acc[i][j], 0, 0, 0);

    asm volatile("s_waitcnt lgkmcnt(0)" ::: "memory");  // my LDS reads complete
    asm volatile("s_barrier" ::: "memory");             // all waves done reading cur
    if (t + 2 < nt) stage(cur, (t + 2) * 32);           // refill freed buffer
  }

  const int lc = lane & 15, lr4 = (lane >> 4) * 4;
#pragma unroll
  for (int i = 0; i < WMR; ++i) {
    const int grow0 = m0 + wr * (WMR * 16) + i * 16 + lr4;
#pragma unroll
    for (int j = 0; j < 4; ++j) {
      const int gcol = n0 + wc * 64 + j * 16 + lc;
      const float bv = bias ? bias[gcol] : 0.f;
#pragma unroll
      for (int r = 0; r < 4; ++r) {
        const size_t oo = (size_t)(grow0 + r) * N + gcol;
        float val = acc[i][j][r] + bv;
        if constexpr (EPI == 1) val += resid[oo];
        if constexpr (EPI == 2) val = 0.5f * val * (1.f + erff(val * 0.70710678118f));
        if constexpr (OBF)
          reinterpret_cast<hb*>(outv)[oo] = __float2bfloat16(val);
        else
          reinterpret_cast<float*>(outv)[oo] = val;
      }
    }
  }
}

// ---------------- lm_head GEMM: 256x256 tile, 8 waves, BK=32, 2-buffer ----------
// Occupancy experiment: 64 KB LDS (2 buffers) -> 2 blocks/CU. Single-phase tile:
//   { vmcnt(4) -> barrier -> 12 ds_read + 32 MFMA (compiler lgkm interleave) ->
//     lgkmcnt(0) -> barrier -> stage(cur, t+2) }
// Stage distance 2 (loads at end of t consumed at t+2, slack ~1 tile); the
// co-resident block's compute covers residual latency (m114 TLP mechanism).
// Chunk-XOR swizzle: 0 bank conflicts (measured R5-R9).
#define MM16(ABASE, AF, BF)                                                     \
  _Pragma("unroll") for (int i_ = 0; i_ < 4; ++i_)                              \
      _Pragma("unroll") for (int j_ = 0; j_ < 4; ++j_)                          \
          acc[(ABASE) + i_][j_] = __builtin_amdgcn_mfma_f32_16x16x32_bf16(      \
              (AF)[i_], (BF)[j_], acc[(ABASE) + i_][j_], 0, 0, 0);

__global__ __launch_bounds__(512, 4) void gemm_lmhead(const hb* __restrict__ A,
                                                      const hb* __restrict__ Bw,
                                                      float* __restrict__ out) {
  constexpr int K = 1024, N = 32000, NT = K / 32;  // 32 K-tiles
  __shared__ __align__(16) hb As[2][256][32];
  __shared__ __align__(16) hb Bs[2][256][32];
  const int tid = threadIdx.x, lane = tid & 63, wid = tid >> 6;
  const int nwg = gridDim.x;
  const int dd = blockIdx.x;
  const int wg = (dd & 7) * (nwg >> 3) + (dd >> 3);  // chunked XCD swizzle
  const int m0 = (wg & 7) * 256;
  const int n0 = (wg >> 3) * 256;
  const int wr = wid >> 2, wc = wid & 3;
  const int lr = lane & 15;
  const int rc8 = (((lane >> 4) ^ ((lr >> 1) & 3)) & 3) * 8;  // swizzled read chunk

  f32x4 acc[8][4];
  const f32x4 z = {0.f, 0.f, 0.f, 0.f};
#pragma unroll
  for (int i = 0; i < 8; ++i)
#pragma unroll
    for (int j = 0; j < 4; ++j) acc[i][j] = z;

  const int rr = tid >> 2;
  const int cs = tid & 3;
  const int cc = cs ^ ((tid >> 3) & 3);

  auto stageA = [&](int b, int t) {
#pragma unroll
    for (int q = 0; q < 2; ++q) {
      const int row = q * 128 + rr;
      __builtin_amdgcn_global_load_lds(
          (gptr_t)(A + (size_t)(m0 + row) * K + t * 32 + cc * 8),
          (lptr_t)(&As[b][row][cs * 8]), 16, 0, 0);
    }
  };
  auto stageB = [&](int b, int t) {
#pragma unroll
    for (int q = 0; q < 2; ++q) {
      const int row = q * 128 + rr;
      __builtin_amdgcn_global_load_lds(
          (gptr_t)(Bw + (size_t)(n0 + row) * K + t * 32 + cc * 8),
          (lptr_t)(&Bs[b][row][cs * 8]), 16, 0, 0);
    }
  };
  auto dsA = [&](int b, int mh, bf16x8* af) {
#pragma unroll
    for (int i = 0; i < 4; ++i)
      af[i] = *reinterpret_cast<const bf16x8*>(
          &As[b][wr * 128 + mh * 64 + i * 16 + lr][rc8]);
  };
  auto dsB = [&](int b, bf16x8* bf) {
#pragma unroll
    for (int j = 0; j < 4; ++j)
      bf[j] = *reinterpret_cast<const bf16x8*>(&Bs[b][wc * 64 + j * 16 + lr][rc8]);
  };

  // single-phase tile body; stage distance 2 over 2 buffers
  auto tile = [&](int t, bool stg, bool last) {
    const int c = t & 1;
    if (last)
      asm volatile("s_waitcnt vmcnt(0)" ::: "memory");
    else
      asm volatile("s_waitcnt vmcnt(4)" ::: "memory");
    __builtin_amdgcn_s_barrier();  // all waves: buf c resident
    bf16x8 af0[4], bf[4], af1[4];
    dsA(c, 0, af0);
    dsB(c, bf);
    dsA(c, 1, af1);
    __builtin_amdgcn_s_setprio(1);
    MM16(0, af0, bf)
    MM16(4, af1, bf)
    __builtin_amdgcn_s_setprio(0);
    asm volatile("s_waitcnt lgkmcnt(0)" ::: "memory");  // my reads of buf c done
    __builtin_amdgcn_s_barrier();                       // all waves done with buf c
    if (stg) { stageA(c, t + 2); stageB(c, t + 2); }    // refill freed buffer
  };

  // prologue: stage tiles 0,1 (8 loads in flight)
  stageA(0, 0); stageB(0, 0);
  stageA(1, 1); stageB(1, 1);

  for (int t = 0; t < NT - 1; ++t) tile(t, t + 2 < NT, false);
  tile(NT - 1, false, true);

  // epilogue
  const int lc = lane & 15, lr4 = (lane >> 4) * 4;
#pragma unroll
  for (int i2 = 0; i2 < 8; ++i2) {
    const int grow0 = m0 + wr * 128 + i2 * 16 + lr4;
#pragma unroll
    for (int j = 0; j < 4; ++j) {
      const int gcol = n0 + wc * 64 + j * 16 + lc;
#pragma unroll
      for (int r = 0; r < 4; ++r)
        out[(size_t)(grow0 + r) * N + gcol] = acc[i2][j][r];
    }
  }
}

// ---------------- host ----------------
extern "C" void kernel_launch(void* const* d_in, const int* in_sizes, int n_in,
                              void* d_out, int out_size, void* d_ws, size_t ws_size,
                              hipStream_t stream) {
  const int* idx = (const int*)d_in[0];
  const float* wte = (const float*)d_in[1];
  const float* wpe = (const float*)d_in[2];
  const float* ln1_w = (const float*)d_in[3];
  const float* ln1_b = (const float*)d_in[4];
  const float* qkv_w = (const float*)d_in[5];
  const float* qkv_b = (const float*)d_in[6];
  const float* proj_w = (const float*)d_in[7];
  const float* proj_b = (const float*)d_in[8];
  const float* ln2_w = (const float*)d_in[9];
  const float* ln2_b = (const float*)d_in[10];
  const float* fc1_w = (const float*)d_in[11];
  const float* fc1_b = (const float*)d_in[12];
  const float* fc2_w = (const float*)d_in[13];
  const float* fc2_b = (const float*)d_in[14];
  const float* lnf_w = (const float*)d_in[15];
  const float* lnf_b = (const float*)d_in[16];

  char* ws = (char*)d_ws;
  size_t off = 0;
  auto alloc = [&](size_t bytes) -> void* {
    void* p = ws + off;
    off += (bytes + 255) & ~(size_t)255;
    return p;
  };
  hb* wte_bf = (hb*)alloc((size_t)V_ * D_ * 2);
  hb* qkvw_bf = (hb*)alloc((size_t)L_ * 3 * D_ * D_ * 2);
  hb* projw_bf = (hb*)alloc((size_t)L_ * D_ * D_ * 2);
  hb* fc1w_bf = (hb*)alloc((size_t)L_ * DFF_ * D_ * 2);
  hb* fc2w_bf = (hb*)alloc((size_t)L_ * D_ * DFF_ * 2);
  float* x = (float*)alloc((size_t)BT * D_ * 4);
  hb* hbuf = (hb*)alloc((size_t)BT * D_ * 2);
  hb* qkvbuf = (hb*)alloc((size_t)BT * 3 * D_ * 2);
  hb* ybuf = (hb*)alloc((size_t)BT * D_ * 2);
  hb* gbuf = (hb*)alloc((size_t)BT * DFF_ * 2);
  hb* vtbuf = (hb*)alloc((size_t)B_ * H_ * HD_ * T_ * 2);

  k_cast5<<<4096, 256, 0, stream>>>(
      wte, wte_bf, (int)((size_t)V_ * D_ / 4),
      qkv_w, qkvw_bf, (int)((size_t)L_ * 3 * D_ * D_ / 4),
      proj_w, projw_bf, (int)((size_t)L_ * D_ * D_ / 4),
      fc1_w, fc1w_bf, (int)((size_t)L_ * DFF_ * D_ / 4),
      fc2_w, fc2w_bf, (int)((size_t)L_ * D_ * DFF_ / 4));

  k_embed_ln<<<BT, 256, 0, stream>>>(idx, wte, wpe, ln1_w, ln1_b, x, hbuf);

  for (int l = 0; l < L_; ++l) {
    if (l) k_ln<<<BT, 256, 0, stream>>>(x, ln1_w + l * D_, ln1_b + l * D_, hbuf);
    gemm_bt<0, true, 128><<<MTILES * (3 * D_ / 128), 256, 0, stream>>>(
        hbuf, qkvw_bf + (size_t)l * 3 * D_ * D_, qkv_b + (size_t)l * 3 * D_, nullptr,
        qkvbuf, BT, 3 * D_, D_);
    k_vtrans<<<dim3(B_ * H_, T_ / 64), 256, 0, stream>>>(qkvbuf, vtbuf);
    k_attn<<<(B_ * H_ * (T_ / 16)) / 4, 256, 0, stream>>>(qkvbuf, vtbuf, ybuf);
    gemm_bt<1, false, 64><<<MTILES * (D_ / 64), 256, 0, stream>>>(
        ybuf, projw_bf + (size_t)l * D_ * D_, proj_b + (size_t)l * D_, x, x, BT, D_, D_);
    k_ln<<<BT, 256, 0, stream>>>(x, ln2_w + l * D_, ln2_b + l * D_, hbuf);
    gemm_bt<2, true, 128><<<MTILES * (DFF_ / 128), 256, 0, stream>>>(
        hbuf, fc1w_bf + (size_t)l * DFF_ * D_, fc1_b + (size_t)l * DFF_, nullptr,
        gbuf, BT, DFF_, D_);
    gemm_bt<1, false, 64><<<MTILES * (D_ / 64), 256, 0, stream>>>(
        gbuf, fc2w_bf + (size_t)l * D_ * DFF_, fc2_b + (size_t)l * D_, x, x, BT, D_, DFF_);
  }

  k_ln<<<BT, 256, 0, stream>>>(x, lnf_w, lnf_b, hbuf);
  gemm_lmhead<<<8 * (V_ / 256), 512, 0, stream>>>(hbuf, wte_bf, (float*)d_out);
}

// Round 11
// 1281.317 us; speedup vs baseline: 1.8460x; 1.8460x over previous
//
#include <hip/hip_runtime.h>
#include <hip/hip_bf16.h>
#include <cstdint>
#include <cstddef>

using hb = __hip_bfloat16;
typedef __bf16 bf16x8 __attribute__((ext_vector_type(8)));
typedef float f32x4 __attribute__((ext_vector_type(4)));
typedef const __attribute__((address_space(1))) void* gptr_t;
typedef __attribute__((address_space(3))) void* lptr_t;

namespace {
constexpr int L_ = 4, V_ = 32000, D_ = 1024, H_ = 16, DFF_ = 4096, HD_ = 64;
constexpr int B_ = 2, T_ = 1024;
constexpr int BT = B_ * T_;  // 2048 rows
constexpr int PSTR = 56;     // P-tile LDS row stride (elems): 112B, 16B-aligned
constexpr int MTILES = BT / 128;  // 16 M-tiles for 128-row GEMMs
}

// ---------------- merged weight cast f32 -> bf16 (1 dispatch for all 5) --------
__device__ __forceinline__ void cast_range(const float* __restrict__ in,
                                           hb* __restrict__ out, int n4,
                                           int base, int stride) {
  for (int i = base; i < n4; i += stride) {
    float4 v = reinterpret_cast<const float4*>(in)[i];
    union { hb h[4]; ushort4 u; } t;
    t.h[0] = __float2bfloat16(v.x);
    t.h[1] = __float2bfloat16(v.y);
    t.h[2] = __float2bfloat16(v.z);
    t.h[3] = __float2bfloat16(v.w);
    reinterpret_cast<ushort4*>(out)[i] = t.u;
  }
}

__global__ __launch_bounds__(256) void k_cast5(
    const float* s0, hb* d0, int n0, const float* s1, hb* d1, int n1,
    const float* s2, hb* d2, int n2, const float* s3, hb* d3, int n3,
    const float* s4, hb* d4, int n4) {
  const int base = blockIdx.x * 256 + threadIdx.x;
  const int stride = gridDim.x * 256;
  cast_range(s0, d0, n0, base, stride);
  cast_range(s1, d1, n1, base, stride);
  cast_range(s2, d2, n2, base, stride);
  cast_range(s3, d3, n3, base, stride);
  cast_range(s4, d4, n4, base, stride);
}

// ---------------- fused embedding + layer-0 ln1 ----------------
// x = wte[idx] + wpe (fp32, kept as residual); out = LN(x) in bf16.
__global__ __launch_bounds__(256) void k_embed_ln(const int* __restrict__ idx,
                                                  const float* __restrict__ wte,
                                                  const float* __restrict__ wpe,
                                                  const float* __restrict__ w,
                                                  const float* __restrict__ b,
                                                  float* __restrict__ x,
                                                  hb* __restrict__ out) {
  const int row = blockIdx.x;
  const int tid = threadIdx.x;
  const int t = row & (T_ - 1);
  const int tok = idx[row];
  const float4 a = reinterpret_cast<const float4*>(wte + (size_t)tok * D_)[tid];
  const float4 p = reinterpret_cast<const float4*>(wpe + (size_t)t * D_)[tid];
  const float4 v = {a.x + p.x, a.y + p.y, a.z + p.z, a.w + p.w};
  reinterpret_cast<float4*>(x + (size_t)row * D_)[tid] = v;
  float s = v.x + v.y + v.z + v.w;
  float ss = v.x * v.x + v.y * v.y + v.z * v.z + v.w * v.w;
#pragma unroll
  for (int o = 32; o; o >>= 1) { s += __shfl_xor(s, o); ss += __shfl_xor(ss, o); }
  __shared__ float rs[4], rss[4];
  const int wid = tid >> 6;
  if ((tid & 63) == 0) { rs[wid] = s; rss[wid] = ss; }
  __syncthreads();
  s = rs[0] + rs[1] + rs[2] + rs[3];
  ss = rss[0] + rss[1] + rss[2] + rss[3];
  const float mu = s * (1.f / D_);
  const float var = ss * (1.f / D_) - mu * mu;
  const float rstd = rsqrtf(var + 1e-5f);
  const float4 wv = reinterpret_cast<const float4*>(w)[tid];
  const float4 bv = reinterpret_cast<const float4*>(b)[tid];
  union { hb h[4]; ushort4 u; } o2;
  o2.h[0] = __float2bfloat16((v.x - mu) * rstd * wv.x + bv.x);
  o2.h[1] = __float2bfloat16((v.y - mu) * rstd * wv.y + bv.y);
  o2.h[2] = __float2bfloat16((v.z - mu) * rstd * wv.z + bv.z);
  o2.h[3] = __float2bfloat16((v.w - mu) * rstd * wv.w + bv.w);
  reinterpret_cast<ushort4*>(out + (size_t)row * D_)[tid] = o2.u;
}

// ---------------- layernorm: fp32 in -> bf16 out ----------------
__global__ __launch_bounds__(256) void k_ln(const float* __restrict__ x,
                                            const float* __restrict__ w,
                                            const float* __restrict__ b,
                                            hb* __restrict__ out) {
  const int row = blockIdx.x;
  const int tid = threadIdx.x;
  const float4 v = reinterpret_cast<const float4*>(x + (size_t)row * D_)[tid];
  float s = v.x + v.y + v.z + v.w;
  float ss = v.x * v.x + v.y * v.y + v.z * v.z + v.w * v.w;
#pragma unroll
  for (int o = 32; o; o >>= 1) { s += __shfl_xor(s, o); ss += __shfl_xor(ss, o); }
  __shared__ float rs[4], rss[4];
  const int wid = tid >> 6;
  if ((tid & 63) == 0) { rs[wid] = s; rss[wid] = ss; }
  __syncthreads();
  s = rs[0] + rs[1] + rs[2] + rs[3];
  ss = rss[0] + rss[1] + rss[2] + rss[3];
  const float mu = s * (1.f / D_);
  const float var = ss * (1.f / D_) - mu * mu;
  const float rstd = rsqrtf(var + 1e-5f);
  const float4 wv = reinterpret_cast<const float4*>(w)[tid];
  const float4 bv = reinterpret_cast<const float4*>(b)[tid];
  union { hb h[4]; ushort4 u; } t;
  t.h[0] = __float2bfloat16((v.x - mu) * rstd * wv.x + bv.x);
  t.h[1] = __float2bfloat16((v.y - mu) * rstd * wv.y + bv.y);
  t.h[2] = __float2bfloat16((v.z - mu) * rstd * wv.z + bv.z);
  t.h[3] = __float2bfloat16((v.w - mu) * rstd * wv.w + bv.w);
  reinterpret_cast<ushort4*>(out + (size_t)row * D_)[tid] = t.u;
}

// ---------------- V transpose: qkv[b][t][2D+h*64+d] -> vt[bh][d][t] ----------------
__global__ __launch_bounds__(256) void k_vtrans(const hb* __restrict__ qkv,
                                                hb* __restrict__ vt) {
  // grid: (B*H, T/64)
  __shared__ __align__(16) hb tile[64][66];
  const int bh = blockIdx.x;
  const int b = bh >> 4, h = bh & (H_ - 1);
  const int t0 = blockIdx.y * 64;
  const int tid = threadIdx.x;
  const int tl = tid >> 2, dc = (tid & 3) * 16;
  const hb* src = qkv + ((size_t)(b * T_ + t0 + tl) * 3 * D_) + 2 * D_ + h * HD_ + dc;
  *reinterpret_cast<bf16x8*>(&tile[tl][dc]) = *reinterpret_cast<const bf16x8*>(src);
  *reinterpret_cast<bf16x8*>(&tile[tl][dc + 8]) = *reinterpret_cast<const bf16x8*>(src + 8);
  __syncthreads();
  const int d = tid & 63, tj = tid >> 6;
  hb o[16];
#pragma unroll
  for (int j = 0; j < 16; ++j) o[j] = tile[tj * 16 + j][d];
  bf16x8* dst = reinterpret_cast<bf16x8*>(vt + ((size_t)bh * HD_ + d) * T_ + t0 + tj * 16);
  dst[0] = *reinterpret_cast<bf16x8*>(&o[0]);
  dst[1] = *reinterpret_cast<bf16x8*>(&o[8]);
}

// ---------------- flash attention: wave per 16-query tile, MFMA ----------------
__global__ __launch_bounds__(256) void k_attn(const hb* __restrict__ qkv,
                                              const hb* __restrict__ vt,
                                              hb* __restrict__ y) {
  const int lane = threadIdx.x & 63;
  const int wid = threadIdx.x >> 6;
  const int gw = blockIdx.x * 4 + wid;     // global wave = (bh, qtile)
  const int qt = 63 - (gw & 63);           // heavy tiles first
  const int bh = gw >> 6;
  const int h = bh & (H_ - 1), b = bh >> 4;
  const int q0 = qt * 16;
  const int lr = lane & 15, g = lane >> 4;

  __shared__ __align__(16) hb plds[4][16 * PSTR];
  hb* pw = plds[wid];

  const size_t qrow = ((size_t)(b * T_ + q0 + lr) * 3 * D_) + (size_t)h * HD_;
  const bf16x8 qa0 = *reinterpret_cast<const bf16x8*>(qkv + qrow + g * 8);
  const bf16x8 qa1 = *reinterpret_cast<const bf16x8*>(qkv + qrow + 32 + g * 8);

  const f32x4 z = {0.f, 0.f, 0.f, 0.f};
  float m[4] = {-1e30f, -1e30f, -1e30f, -1e30f};
  float lsum[4] = {0.f, 0.f, 0.f, 0.f};
  f32x4 o[4];
#pragma unroll
  for (int i = 0; i < 4; ++i) o[i] = z;

  const int nkv = (q0 + 47) >> 5;  // ceil((q0+16)/32) tiles of 32 keys
  for (int kt = 0; kt < nkv; ++kt) {
    const int kv0 = kt * 32;
    f32x4 s[2];
#pragma unroll
    for (int nt = 0; nt < 2; ++nt) {
      const size_t krow =
          ((size_t)(b * T_ + kv0 + nt * 16 + lr) * 3 * D_) + D_ + (size_t)h * HD_;
      const bf16x8 kb0 = *reinterpret_cast<const bf16x8*>(qkv + krow + g * 8);
      const bf16x8 kb1 = *reinterpret_cast<const bf16x8*>(qkv + krow + 32 + g * 8);
      f32x4 acc = z;
      acc = __builtin_amdgcn_mfma_f32_16x16x32_bf16(qa0, kb0, acc, 0, 0, 0);
      acc = __builtin_amdgcn_mfma_f32_16x16x32_bf16(qa1, kb1, acc, 0, 0, 0);
      s[nt] = acc;
    }
    // C layout: col = lane&15 (kv), row = g*4+r (q)   [verified m89]
#pragma unroll
    for (int r = 0; r < 4; ++r) {
      const int qg = q0 + g * 4 + r;
      const float s0 = (kv0 + lr <= qg) ? s[0][r] * 0.125f : -1e30f;
      const float s1 = (kv0 + 16 + lr <= qg) ? s[1][r] * 0.125f : -1e30f;
      float rmax = fmaxf(s0, s1);
#pragma unroll
      for (int off = 1; off < 16; off <<= 1) rmax = fmaxf(rmax, __shfl_xor(rmax, off));
      const float mn = fmaxf(m[r], rmax);
      const float c = __expf(m[r] - mn);
      m[r] = mn;
      const float p0 = __expf(s0 - mn);
      const float p1 = __expf(s1 - mn);
      float ps = p0 + p1;
#pragma unroll
      for (int off = 1; off < 16; off <<= 1) ps += __shfl_xor(ps, off);
      lsum[r] = lsum[r] * c + ps;
#pragma unroll
      for (int dt = 0; dt < 4; ++dt) o[dt][r] *= c;
      pw[(g * 4 + r) * PSTR + lr] = __float2bfloat16(p0);
      pw[(g * 4 + r) * PSTR + 16 + lr] = __float2bfloat16(p1);
    }
    // P A-frag: row=lane&15 (q), k=(lane>>4)*8 (kv)
    const bf16x8 pa = *reinterpret_cast<const bf16x8*>(&pw[lr * PSTR + g * 8]);
#pragma unroll
    for (int dt = 0; dt < 4; ++dt) {
      const bf16x8 vb = *reinterpret_cast<const bf16x8*>(
          vt + ((size_t)bh * HD_ + dt * 16 + lr) * T_ + kv0 + g * 8);
      o[dt] = __builtin_amdgcn_mfma_f32_16x16x32_bf16(pa, vb, o[dt], 0, 0, 0);
    }
  }
#pragma unroll
  for (int dt = 0; dt < 4; ++dt) {
#pragma unroll
    for (int r = 0; r < 4; ++r) {
      const size_t oo =
          ((size_t)(b * T_ + q0 + g * 4 + r) * D_) + h * HD_ + dt * 16 + lr;
      y[oo] = __float2bfloat16(o[dt][r] / lsum[r]);
    }
  }
}

// ---------------- layer GEMM (128-row tiles, counted-vmcnt dbuf) ----------------
template <int EPI, bool OBF, int BN>
__global__ __launch_bounds__(256) void gemm_bt(const hb* __restrict__ A,
                                               const hb* __restrict__ Bw,
                                               const float* __restrict__ bias,
                                               const float* resid,
                                               void* outv, int M, int N, int K) {
  constexpr int WMR = (BN == 128) ? 4 : 2;  // 16-row fragments per wave
  __shared__ __align__(16) hb As[2][128 * 32];
  __shared__ __align__(16) hb Bs[2][BN * 32];
  const int tid = threadIdx.x, lane = tid & 63, wid = tid >> 6;

  const int nwg = gridDim.x;
  const int d = blockIdx.x;
  const int wg = (d & 7) * (nwg >> 3) + (d >> 3);
  const int m0 = (wg & (MTILES - 1)) * 128;
  const int n0 = (wg / MTILES) * BN;

  const int wr = (BN == 128) ? (wid >> 1) : wid;
  const int wc = (BN == 128) ? (wid & 1) : 0;

  f32x4 acc[WMR][4];
  const f32x4 z = {0.f, 0.f, 0.f, 0.f};
#pragma unroll
  for (int i = 0; i < WMR; ++i)
#pragma unroll
    for (int j = 0; j < 4; ++j) acc[i][j] = z;

  const int e0 = tid * 8;
  auto stage = [&](int buf, int k0) {
#pragma unroll
    for (int r = 0; r < 2; ++r) {
      const int e = e0 + r * 2048;
      const int row = e >> 5, col = e & 31;
      __builtin_amdgcn_global_load_lds(
          (gptr_t)(A + (size_t)(m0 + row) * K + k0 + col), (lptr_t)(&As[buf][e]), 16, 0, 0);
    }
#pragma unroll
    for (int r = 0; r < BN / 64; ++r) {
      const int e = e0 + r * 2048;
      const int row = e >> 5, col = e & 31;
      __builtin_amdgcn_global_load_lds(
          (gptr_t)(Bw + (size_t)(n0 + row) * K + k0 + col), (lptr_t)(&Bs[buf][e]), 16, 0, 0);
    }
  };

  stage(0, 0);
  stage(1, 32);

  const int nt = K >> 5;
  const int lr = lane & 15, lk = (lane >> 4) * 8;
  for (int t = 0; t < nt; ++t) {
    const int cur = t & 1;
    if (t + 1 < nt) {
      if constexpr (BN == 128)
        asm volatile("s_waitcnt vmcnt(4)" ::: "memory");
      else
        asm volatile("s_waitcnt vmcnt(3)" ::: "memory");
    } else {
      asm volatile("s_waitcnt vmcnt(0)" ::: "memory");
    }
    asm volatile("s_barrier" ::: "memory");  // all waves: buf cur resident

    bf16x8 af[WMR], bfr[4];
#pragma unroll
    for (int i = 0; i < WMR; ++i)
      af[i] = *reinterpret_cast<const bf16x8*>(
          &As[cur][(wr * (WMR * 16) + i * 16 + lr) * 32 + lk]);
#pragma unroll
    for (int j = 0; j < 4; ++j)
      bfr[j] = *reinterpret_cast<const bf16x8*>(
          &Bs[cur][(wc * 64 + j * 16 + lr) * 32 + lk]);
#pragma unroll
    for (int i = 0; i < WMR; ++i)
#pragma unroll
      for (int j = 0; j < 4; ++j)
        acc[i][j] = __builtin_amdgcn_mfma_f32_16x16x32_bf16(af[i], bfr[j], acc[i][j], 0, 0, 0);

    asm volatile("s_waitcnt lgkmcnt(0)" ::: "memory");  // my LDS reads complete
    asm volatile("s_barrier" ::: "memory");             // all waves done reading cur
    if (t + 2 < nt) stage(cur, (t + 2) * 32);           // refill freed buffer
  }

  const int lc = lane & 15, lr4 = (lane >> 4) * 4;
#pragma unroll
  for (int i = 0; i < WMR; ++i) {
    const int grow0 = m0 + wr * (WMR * 16) + i * 16 + lr4;
#pragma unroll
    for (int j = 0; j < 4; ++j) {
      const int gcol = n0 + wc * 64 + j * 16 + lc;
      const float bv = bias ? bias[gcol] : 0.f;
#pragma unroll
      for (int r = 0; r < 4; ++r) {
        const size_t oo = (size_t)(grow0 + r) * N + gcol;
        float val = acc[i][j][r] + bv;
        if constexpr (EPI == 1) val += resid[oo];
        if constexpr (EPI == 2) val = 0.5f * val * (1.f + erff(val * 0.70710678118f));
        if constexpr (OBF)
          reinterpret_cast<hb*>(outv)[oo] = __float2bfloat16(val);
        else
          reinterpret_cast<float*>(outv)[oo] = val;
      }
    }
  }
}

// ---------------- lm_head GEMM: 256x256 tile, 8 waves, BK=32, 4-buffer pipeline --
// R6 body (best measured: 174 us; VGPR 92, 1 block/CU — do NOT raise min-waves,
// R10 showed launch_bounds(512,4) caps VGPR at 128 and spills acc to scratch).
// 2 sub-phases per K-tile, stage distance 3, per-tile counted vmcnt(8).
// Chunk-XOR swizzle: 0 bank conflicts (measured R5-R9).
#define MM16(ABASE, AF, BF)                                                     \
  _Pragma("unroll") for (int i_ = 0; i_ < 4; ++i_)                              \
      _Pragma("unroll") for (int j_ = 0; j_ < 4; ++j_)                          \
          acc[(ABASE) + i_][j_] = __builtin_amdgcn_mfma_f32_16x16x32_bf16(      \
              (AF)[i_], (BF)[j_], acc[(ABASE) + i_][j_], 0, 0, 0);

__global__ __launch_bounds__(512, 2) void gemm_lmhead(const hb* __restrict__ A,
                                                      const hb* __restrict__ Bw,
                                                      float* __restrict__ out) {
  constexpr int K = 1024, N = 32000, NT = K / 32;  // 32 K-tiles
  __shared__ __align__(16) hb As[4][256][32];
  __shared__ __align__(16) hb Bs[4][256][32];
  const int tid = threadIdx.x, lane = tid & 63, wid = tid >> 6;
  const int nwg = gridDim.x;
  const int dd = blockIdx.x;
  const int wg = (dd & 7) * (nwg >> 3) + (dd >> 3);  // chunked XCD swizzle
  const int m0 = (wg & 7) * 256;
  const int n0 = (wg >> 3) * 256;
  const int wr = wid >> 2, wc = wid & 3;
  const int lr = lane & 15;
  const int rc8 = (((lane >> 4) ^ ((lr >> 1) & 3)) & 3) * 8;  // swizzled read chunk

  f32x4 acc[8][4];
  const f32x4 z = {0.f, 0.f, 0.f, 0.f};
#pragma unroll
  for (int i = 0; i < 8; ++i)
#pragma unroll
    for (int j = 0; j < 4; ++j) acc[i][j] = z;

  const int rr = tid >> 2;
  const int cs = tid & 3;
  const int cc = cs ^ ((tid >> 3) & 3);

  auto stageA = [&](int b, int t) {
#pragma unroll
    for (int q = 0; q < 2; ++q) {
      const int row = q * 128 + rr;
      __builtin_amdgcn_global_load_lds(
          (gptr_t)(A + (size_t)(m0 + row) * K + t * 32 + cc * 8),
          (lptr_t)(&As[b][row][cs * 8]), 16, 0, 0);
    }
  };
  auto stageB = [&](int b, int t) {
#pragma unroll
    for (int q = 0; q < 2; ++q) {
      const int row = q * 128 + rr;
      __builtin_amdgcn_global_load_lds(
          (gptr_t)(Bw + (size_t)(n0 + row) * K + t * 32 + cc * 8),
          (lptr_t)(&Bs[b][row][cs * 8]), 16, 0, 0);
    }
  };
  auto dsA = [&](int b, int mh, bf16x8* af) {
#pragma unroll
    for (int i = 0; i < 4; ++i)
      af[i] = *reinterpret_cast<const bf16x8*>(
          &As[b][wr * 128 + mh * 64 + i * 16 + lr][rc8]);
  };
  auto dsB = [&](int b, bf16x8* bf) {
#pragma unroll
    for (int j = 0; j < 4; ++j)
      bf[j] = *reinterpret_cast<const bf16x8*>(&Bs[b][wc * 64 + j * 16 + lr][rc8]);
  };

  // R6 2-sub-phase tile body; vm = vmcnt immediate (-1 = none); stg = stage t+3
  auto tile = [&](int t, bool stg, int vm) {
    const int c = t & 3;
    const int b3 = (t + 3) & 3;
    bf16x8 af[4], bf[4];
    // Phase A (mh=0): 8 ds_read + stage A-unit
    dsA(c, 0, af);
    dsB(c, bf);
    if (stg) stageA(b3, t + 3);
    __builtin_amdgcn_s_barrier();
    asm volatile("s_waitcnt lgkmcnt(0)" ::: "memory");
    __builtin_amdgcn_s_setprio(1);
    MM16(0, af, bf)
    __builtin_amdgcn_s_setprio(0);
    __builtin_amdgcn_s_barrier();
    // Phase B (mh=1): 4 ds_read + stage B-unit + per-tile vmcnt
    dsA(c, 1, af);
    if (stg) stageB(b3, t + 3);
    if (vm == 8)
      asm volatile("s_waitcnt vmcnt(8)" ::: "memory");
    else if (vm == 4)
      asm volatile("s_waitcnt vmcnt(4)" ::: "memory");
    else if (vm == 0)
      asm volatile("s_waitcnt vmcnt(0)" ::: "memory");
    __builtin_amdgcn_s_barrier();
    asm volatile("s_waitcnt lgkmcnt(0)" ::: "memory");
    __builtin_amdgcn_s_setprio(1);
    MM16(4, af, bf)
    __builtin_amdgcn_s_setprio(0);
    __builtin_amdgcn_s_barrier();
  };

  // prologue: stage tiles 0,1,2 (12 loads); retire tile 0's 4 -> vmcnt(8)
  stageA(0, 0); stageB(0, 0);
  stageA(1, 1); stageB(1, 1);
  stageA(2, 2); stageB(2, 2);
  asm volatile("s_waitcnt vmcnt(8)" ::: "memory");
  __builtin_amdgcn_s_barrier();

  for (int t = 0; t < NT - 3; ++t) tile(t, true, 8);
  tile(NT - 3, false, 4);
  tile(NT - 2, false, 0);
  tile(NT - 1, false, -1);

  // epilogue
  const int lc = lane & 15, lr4 = (lane >> 4) * 4;
#pragma unroll
  for (int i2 = 0; i2 < 8; ++i2) {
    const int grow0 = m0 + wr * 128 + i2 * 16 + lr4;
#pragma unroll
    for (int j = 0; j < 4; ++j) {
      const int gcol = n0 + wc * 64 + j * 16 + lc;
#pragma unroll
      for (int r = 0; r < 4; ++r)
        out[(size_t)(grow0 + r) * N + gcol] = acc[i2][j][r];
    }
  }
}

// ---------------- host ----------------
extern "C" void kernel_launch(void* const* d_in, const int* in_sizes, int n_in,
                              void* d_out, int out_size, void* d_ws, size_t ws_size,
                              hipStream_t stream) {
  const int* idx = (const int*)d_in[0];
  const float* wte = (const float*)d_in[1];
  const float* wpe = (const float*)d_in[2];
  const float* ln1_w = (const float*)d_in[3];
  const float* ln1_b = (const float*)d_in[4];
  const float* qkv_w = (const float*)d_in[5];
  const float* qkv_b = (const float*)d_in[6];
  const float* proj_w = (const float*)d_in[7];
  const float* proj_b = (const float*)d_in[8];
  const float* ln2_w = (const float*)d_in[9];
  const float* ln2_b = (const float*)d_in[10];
  const float* fc1_w = (const float*)d_in[11];
  const float* fc1_b = (const float*)d_in[12];
  const float* fc2_w = (const float*)d_in[13];
  const float* fc2_b = (const float*)d_in[14];
  const float* lnf_w = (const float*)d_in[15];
  const float* lnf_b = (const float*)d_in[16];

  char* ws = (char*)d_ws;
  size_t off = 0;
  auto alloc = [&](size_t bytes) -> void* {
    void* p = ws + off;
    off += (bytes + 255) & ~(size_t)255;
    return p;
  };
  hb* wte_bf = (hb*)alloc((size_t)V_ * D_ * 2);
  hb* qkvw_bf = (hb*)alloc((size_t)L_ * 3 * D_ * D_ * 2);
  hb* projw_bf = (hb*)alloc((size_t)L_ * D_ * D_ * 2);
  hb* fc1w_bf = (hb*)alloc((size_t)L_ * DFF_ * D_ * 2);
  hb* fc2w_bf = (hb*)alloc((size_t)L_ * D_ * DFF_ * 2);
  float* x = (float*)alloc((size_t)BT * D_ * 4);
  hb* hbuf = (hb*)alloc((size_t)BT * D_ * 2);
  hb* qkvbuf = (hb*)alloc((size_t)BT * 3 * D_ * 2);
  hb* ybuf = (hb*)alloc((size_t)BT * D_ * 2);
  hb* gbuf = (hb*)alloc((size_t)BT * DFF_ * 2);
  hb* vtbuf = (hb*)alloc((size_t)B_ * H_ * HD_ * T_ * 2);

  k_cast5<<<4096, 256, 0, stream>>>(
      wte, wte_bf, (int)((size_t)V_ * D_ / 4),
      qkv_w, qkvw_bf, (int)((size_t)L_ * 3 * D_ * D_ / 4),
      proj_w, projw_bf, (int)((size_t)L_ * D_ * D_ / 4),
      fc1_w, fc1w_bf, (int)((size_t)L_ * DFF_ * D_ / 4),
      fc2_w, fc2w_bf, (int)((size_t)L_ * D_ * DFF_ / 4));

  k_embed_ln<<<BT, 256, 0, stream>>>(idx, wte, wpe, ln1_w, ln1_b, x, hbuf);

  for (int l = 0; l < L_; ++l) {
    if (l) k_ln<<<BT, 256, 0, stream>>>(x, ln1_w + l * D_, ln1_b + l * D_, hbuf);
    gemm_bt<0, true, 128><<<MTILES * (3 * D_ / 128), 256, 0, stream>>>(
        hbuf, qkvw_bf + (size_t)l * 3 * D_ * D_, qkv_b + (size_t)l * 3 * D_, nullptr,
        qkvbuf, BT, 3 * D_, D_);
    k_vtrans<<<dim3(B_ * H_, T_ / 64), 256, 0, stream>>>(qkvbuf, vtbuf);
    k_attn<<<(B_ * H_ * (T_ / 16)) / 4, 256, 0, stream>>>(qkvbuf, vtbuf, ybuf);
    gemm_bt<1, false, 64><<<MTILES * (D_ / 64), 256, 0, stream>>>(
        ybuf, projw_bf + (size_t)l * D_ * D_, proj_b + (size_t)l * D_, x, x, BT, D_, D_);
    k_ln<<<BT, 256, 0, stream>>>(x, ln2_w + l * D_, ln2_b + l * D_, hbuf);
    gemm_bt<2, true, 128><<<MTILES * (DFF_ / 128), 256, 0, stream>>>(
        hbuf, fc1w_bf + (size_t)l * DFF_ * D_, fc1_b + (size_t)l * DFF_, nullptr,
        gbuf, BT, DFF_, D_);
    gemm_bt<1, false, 64><<<MTILES * (D_ / 64), 256, 0, stream>>>(
        gbuf, fc2w_bf + (size_t)l * D_ * DFF_, fc2_b + (size_t)l * D_, x, x, BT, D_, DFF_);
  }

  k_ln<<<BT, 256, 0, stream>>>(x, lnf_w, lnf_b, hbuf);
  gemm_lmhead<<<8 * (V_ / 256), 512, 0, stream>>>(hbuf, wte_bf, (float*)d_out);
}

// Round 12
// 1207.051 us; speedup vs baseline: 1.9596x; 1.0615x over previous
//
#include <hip/hip_runtime.h>
#include <hip/hip_bf16.h>
#include <cstdint>
#include <cstddef>

using hb = __hip_bfloat16;
typedef __bf16 bf16x8 __attribute__((ext_vector_type(8)));
typedef float f32x4 __attribute__((ext_vector_type(4)));
typedef const __attribute__((address_space(1))) void* gptr_t;
typedef __attribute__((address_space(3))) void* lptr_t;

namespace {
constexpr int L_ = 4, V_ = 32000, D_ = 1024, H_ = 16, DFF_ = 4096, HD_ = 64;
constexpr int B_ = 2, T_ = 1024;
constexpr int BT = B_ * T_;  // 2048 rows
constexpr int PSTR = 56;     // P-tile LDS row stride (elems): 112B, 16B-aligned
constexpr int MTILES = BT / 128;  // 16 M-tiles for 128-row GEMMs
}

// ---------------- weight cast f32 -> bf16 (5 separate streaming kernels:
// measured faster than a merged k_cast5 — R6 1213 vs R11 1281) ----------------
__global__ __launch_bounds__(256) void k_cast_bf16(const float* __restrict__ in,
                                                   hb* __restrict__ out, int n4) {
  int i = blockIdx.x * 256 + threadIdx.x;
  const int stride = gridDim.x * 256;
  for (; i < n4; i += stride) {
    float4 v = reinterpret_cast<const float4*>(in)[i];
    union { hb h[4]; ushort4 u; } t;
    t.h[0] = __float2bfloat16(v.x);
    t.h[1] = __float2bfloat16(v.y);
    t.h[2] = __float2bfloat16(v.z);
    t.h[3] = __float2bfloat16(v.w);
    reinterpret_cast<ushort4*>(out)[i] = t.u;
  }
}

// ---------------- embedding: x = wte[idx] + wpe ----------------
__global__ __launch_bounds__(256) void k_embed(const int* __restrict__ idx,
                                               const float* __restrict__ wte,
                                               const float* __restrict__ wpe,
                                               float* __restrict__ x) {
  const int i = blockIdx.x * 256 + threadIdx.x;  // grid covers BT*D exactly
  const int row = i >> 10;   // D = 1024
  const int d = i & 1023;
  const int t = row & (T_ - 1);
  const int tok = idx[row];
  x[i] = wte[(size_t)tok * D_ + d] + wpe[(size_t)t * D_ + d];
}

// ---------------- layernorm: fp32 in -> bf16 out ----------------
__global__ __launch_bounds__(256) void k_ln(const float* __restrict__ x,
                                            const float* __restrict__ w,
                                            const float* __restrict__ b,
                                            hb* __restrict__ out) {
  const int row = blockIdx.x;
  const int tid = threadIdx.x;
  const float4 v = reinterpret_cast<const float4*>(x + (size_t)row * D_)[tid];
  float s = v.x + v.y + v.z + v.w;
  float ss = v.x * v.x + v.y * v.y + v.z * v.z + v.w * v.w;
#pragma unroll
  for (int o = 32; o; o >>= 1) { s += __shfl_xor(s, o); ss += __shfl_xor(ss, o); }
  __shared__ float rs[4], rss[4];
  const int wid = tid >> 6;
  if ((tid & 63) == 0) { rs[wid] = s; rss[wid] = ss; }
  __syncthreads();
  s = rs[0] + rs[1] + rs[2] + rs[3];
  ss = rss[0] + rss[1] + rss[2] + rss[3];
  const float mu = s * (1.f / D_);
  const float var = ss * (1.f / D_) - mu * mu;
  const float rstd = rsqrtf(var + 1e-5f);
  const float4 wv = reinterpret_cast<const float4*>(w)[tid];
  const float4 bv = reinterpret_cast<const float4*>(b)[tid];
  union { hb h[4]; ushort4 u; } t;
  t.h[0] = __float2bfloat16((v.x - mu) * rstd * wv.x + bv.x);
  t.h[1] = __float2bfloat16((v.y - mu) * rstd * wv.y + bv.y);
  t.h[2] = __float2bfloat16((v.z - mu) * rstd * wv.z + bv.z);
  t.h[3] = __float2bfloat16((v.w - mu) * rstd * wv.w + bv.w);
  reinterpret_cast<ushort4*>(out + (size_t)row * D_)[tid] = t.u;
}

// ---------------- V transpose: qkv[b][t][2D+h*64+d] -> vt[bh][d][t] ----------------
__global__ __launch_bounds__(256) void k_vtrans(const hb* __restrict__ qkv,
                                                hb* __restrict__ vt) {
  // grid: (B*H, T/64)
  __shared__ __align__(16) hb tile[64][66];
  const int bh = blockIdx.x;
  const int b = bh >> 4, h = bh & (H_ - 1);
  const int t0 = blockIdx.y * 64;
  const int tid = threadIdx.x;
  const int tl = tid >> 2, dc = (tid & 3) * 16;
  const hb* src = qkv + ((size_t)(b * T_ + t0 + tl) * 3 * D_) + 2 * D_ + h * HD_ + dc;
  *reinterpret_cast<bf16x8*>(&tile[tl][dc]) = *reinterpret_cast<const bf16x8*>(src);
  *reinterpret_cast<bf16x8*>(&tile[tl][dc + 8]) = *reinterpret_cast<const bf16x8*>(src + 8);
  __syncthreads();
  const int d = tid & 63, tj = tid >> 6;
  hb o[16];
#pragma unroll
  for (int j = 0; j < 16; ++j) o[j] = tile[tj * 16 + j][d];
  bf16x8* dst = reinterpret_cast<bf16x8*>(vt + ((size_t)bh * HD_ + d) * T_ + t0 + tj * 16);
  dst[0] = *reinterpret_cast<bf16x8*>(&o[0]);
  dst[1] = *reinterpret_cast<bf16x8*>(&o[8]);
}

// ---------------- flash attention: wave per 16-query tile, MFMA ----------------
__global__ __launch_bounds__(256) void k_attn(const hb* __restrict__ qkv,
                                              const hb* __restrict__ vt,
                                              hb* __restrict__ y) {
  const int lane = threadIdx.x & 63;
  const int wid = threadIdx.x >> 6;
  const int gw = blockIdx.x * 4 + wid;     // global wave = (bh, qtile)
  const int qt = 63 - (gw & 63);           // heavy tiles first
  const int bh = gw >> 6;
  const int h = bh & (H_ - 1), b = bh >> 4;
  const int q0 = qt * 16;
  const int lr = lane & 15, g = lane >> 4;

  __shared__ __align__(16) hb plds[4][16 * PSTR];
  hb* pw = plds[wid];

  const size_t qrow = ((size_t)(b * T_ + q0 + lr) * 3 * D_) + (size_t)h * HD_;
  const bf16x8 qa0 = *reinterpret_cast<const bf16x8*>(qkv + qrow + g * 8);
  const bf16x8 qa1 = *reinterpret_cast<const bf16x8*>(qkv + qrow + 32 + g * 8);

  const f32x4 z = {0.f, 0.f, 0.f, 0.f};
  float m[4] = {-1e30f, -1e30f, -1e30f, -1e30f};
  float lsum[4] = {0.f, 0.f, 0.f, 0.f};
  f32x4 o[4];
#pragma unroll
  for (int i = 0; i < 4; ++i) o[i] = z;

  const int nkv = (q0 + 47) >> 5;  // ceil((q0+16)/32) tiles of 32 keys
  for (int kt = 0; kt < nkv; ++kt) {
    const int kv0 = kt * 32;
    f32x4 s[2];
#pragma unroll
    for (int nt = 0; nt < 2; ++nt) {
      const size_t krow =
          ((size_t)(b * T_ + kv0 + nt * 16 + lr) * 3 * D_) + D_ + (size_t)h * HD_;
      const bf16x8 kb0 = *reinterpret_cast<const bf16x8*>(qkv + krow + g * 8);
      const bf16x8 kb1 = *reinterpret_cast<const bf16x8*>(qkv + krow + 32 + g * 8);
      f32x4 acc = z;
      acc = __builtin_amdgcn_mfma_f32_16x16x32_bf16(qa0, kb0, acc, 0, 0, 0);
      acc = __builtin_amdgcn_mfma_f32_16x16x32_bf16(qa1, kb1, acc, 0, 0, 0);
      s[nt] = acc;
    }
    // C layout: col = lane&15 (kv), row = g*4+r (q)   [verified m89]
#pragma unroll
    for (int r = 0; r < 4; ++r) {
      const int qg = q0 + g * 4 + r;
      const float s0 = (kv0 + lr <= qg) ? s[0][r] * 0.125f : -1e30f;
      const float s1 = (kv0 + 16 + lr <= qg) ? s[1][r] * 0.125f : -1e30f;
      float rmax = fmaxf(s0, s1);
#pragma unroll
      for (int off = 1; off < 16; off <<= 1) rmax = fmaxf(rmax, __shfl_xor(rmax, off));
      const float mn = fmaxf(m[r], rmax);
      const float c = __expf(m[r] - mn);
      m[r] = mn;
      const float p0 = __expf(s0 - mn);
      const float p1 = __expf(s1 - mn);
      float ps = p0 + p1;
#pragma unroll
      for (int off = 1; off < 16; off <<= 1) ps += __shfl_xor(ps, off);
      lsum[r] = lsum[r] * c + ps;
#pragma unroll
      for (int dt = 0; dt < 4; ++dt) o[dt][r] *= c;
      pw[(g * 4 + r) * PSTR + lr] = __float2bfloat16(p0);
      pw[(g * 4 + r) * PSTR + 16 + lr] = __float2bfloat16(p1);
    }
    // P A-frag: row=lane&15 (q), k=(lane>>4)*8 (kv)
    const bf16x8 pa = *reinterpret_cast<const bf16x8*>(&pw[lr * PSTR + g * 8]);
#pragma unroll
    for (int dt = 0; dt < 4; ++dt) {
      const bf16x8 vb = *reinterpret_cast<const bf16x8*>(
          vt + ((size_t)bh * HD_ + dt * 16 + lr) * T_ + kv0 + g * 8);
      o[dt] = __builtin_amdgcn_mfma_f32_16x16x32_bf16(pa, vb, o[dt], 0, 0, 0);
    }
  }
#pragma unroll
  for (int dt = 0; dt < 4; ++dt) {
#pragma unroll
    for (int r = 0; r < 4; ++r) {
      const size_t oo =
          ((size_t)(b * T_ + q0 + g * 4 + r) * D_) + h * HD_ + dt * 16 + lr;
      y[oo] = __float2bfloat16(o[dt][r] / lsum[r]);
    }
  }
}

// ---------------- layer GEMM: 128-row tiles, 3-buffer deep pipeline ----------------
// Ported from the lm_head schedule (R6, measured best): ds_reads issued BEFORE
// the leading barrier (overlap other waves' MFMA tail), stage distance 3 over
// 3 LDS buffers (48 KB / 36 KB -> still 3-4 blocks/CU, avoiding m132's 64 KB
// occupancy cliff), per-tile counted vmcnt(L) retiring exactly the next tile's
// loads. L = loads/tile/thread = 2 (A) + BN/64 (B).
//   prologue: stage t0,t1,t2; vmcnt(2L); barrier          [t0 resident]
//   tile t:   ds_read buf(t%3); vmcnt(L|0|-) ; barrier    [t+1 resident]
//             MFMA; lgkmcnt(0); barrier                   [buf t%3 drained]
//             stage(buf t%3, t+3)                          [refill freed buf]
template <int EPI, bool OBF, int BN>
__global__ __launch_bounds__(256) void gemm_bt(const hb* __restrict__ A,
                                               const hb* __restrict__ Bw,
                                               const float* __restrict__ bias,
                                               const float* resid,
                                               void* outv, int M, int N, int K) {
  constexpr int WMR = (BN == 128) ? 4 : 2;  // 16-row fragments per wave
  __shared__ __align__(16) hb As[3][128 * 32];
  __shared__ __align__(16) hb Bs[3][BN * 32];
  const int tid = threadIdx.x, lane = tid & 63, wid = tid >> 6;

  const int nwg = gridDim.x;
  const int d = blockIdx.x;
  const int wg = (d & 7) * (nwg >> 3) + (d >> 3);
  const int m0 = (wg & (MTILES - 1)) * 128;
  const int n0 = (wg / MTILES) * BN;

  const int wr = (BN == 128) ? (wid >> 1) : wid;
  const int wc = (BN == 128) ? (wid & 1) : 0;

  f32x4 acc[WMR][4];
  const f32x4 z = {0.f, 0.f, 0.f, 0.f};
#pragma unroll
  for (int i = 0; i < WMR; ++i)
#pragma unroll
    for (int j = 0; j < 4; ++j) acc[i][j] = z;

  const int e0 = tid * 8;
  auto stage = [&](int buf, int k0) {
#pragma unroll
    for (int r = 0; r < 2; ++r) {
      const int e = e0 + r * 2048;
      const int row = e >> 5, col = e & 31;
      __builtin_amdgcn_global_load_lds(
          (gptr_t)(A + (size_t)(m0 + row) * K + k0 + col), (lptr_t)(&As[buf][e]), 16, 0, 0);
    }
#pragma unroll
    for (int r = 0; r < BN / 64; ++r) {
      const int e = e0 + r * 2048;
      const int row = e >> 5, col = e & 31;
      __builtin_amdgcn_global_load_lds(
          (gptr_t)(Bw + (size_t)(n0 + row) * K + k0 + col), (lptr_t)(&Bs[buf][e]), 16, 0, 0);
    }
  };

  // prologue: fill all 3 buffers; retire t0's L loads -> vmcnt(2L)
  stage(0, 0);
  stage(1, 32);
  stage(2, 64);
  if constexpr (BN == 128)
    asm volatile("s_waitcnt vmcnt(8)" ::: "memory");
  else
    asm volatile("s_waitcnt vmcnt(6)" ::: "memory");
  asm volatile("s_barrier" ::: "memory");

  const int nt = K >> 5;
  const int lr = lane & 15, lk = (lane >> 4) * 8;
  int cur = 0;
  for (int t = 0; t < nt; ++t) {
    // ds_reads before the leading barrier (residency of cur assured by the
    // previous tile's vmcnt + barrier; prologue covers t=0)
    bf16x8 af[WMR], bfr[4];
#pragma unroll
    for (int i = 0; i < WMR; ++i)
      af[i] = *reinterpret_cast<const bf16x8*>(
          &As[cur][(wr * (WMR * 16) + i * 16 + lr) * 32 + lk]);
#pragma unroll
    for (int j = 0; j < 4; ++j)
      bfr[j] = *reinterpret_cast<const bf16x8*>(
          &Bs[cur][(wc * 64 + j * 16 + lr) * 32 + lk]);

    // counted wait: ensure tile t+1 resident after the barrier.
    // in-flight here: t+1 and (if exists) t+2, staged L each.
    if (t <= nt - 3) {
      if constexpr (BN == 128)
        asm volatile("s_waitcnt vmcnt(4)" ::: "memory");
      else
        asm volatile("s_waitcnt vmcnt(3)" ::: "memory");
    } else if (t == nt - 2) {
      asm volatile("s_waitcnt vmcnt(0)" ::: "memory");
    }
    asm volatile("s_barrier" ::: "memory");

#pragma unroll
    for (int i = 0; i < WMR; ++i)
#pragma unroll
      for (int j = 0; j < 4; ++j)
        acc[i][j] = __builtin_amdgcn_mfma_f32_16x16x32_bf16(af[i], bfr[j], acc[i][j], 0, 0, 0);

    asm volatile("s_waitcnt lgkmcnt(0)" ::: "memory");  // my reads of cur done
    asm volatile("s_barrier" ::: "memory");             // all waves done with cur
    if (t + 3 < nt) stage(cur, (t + 3) * 32);           // refill freed buffer
    cur = (cur == 2) ? 0 : cur + 1;
  }

  const int lc = lane & 15, lr4 = (lane >> 4) * 4;
#pragma unroll
  for (int i = 0; i < WMR; ++i) {
    const int grow0 = m0 + wr * (WMR * 16) + i * 16 + lr4;
#pragma unroll
    for (int j = 0; j < 4; ++j) {
      const int gcol = n0 + wc * 64 + j * 16 + lc;
      const float bv = bias ? bias[gcol] : 0.f;
#pragma unroll
      for (int r = 0; r < 4; ++r) {
        const size_t oo = (size_t)(grow0 + r) * N + gcol;
        float val = acc[i][j][r] + bv;
        if constexpr (EPI == 1) val += resid[oo];
        if constexpr (EPI == 2) val = 0.5f * val * (1.f + erff(val * 0.70710678118f));
        if constexpr (OBF)
          reinterpret_cast<hb*>(outv)[oo] = __float2bfloat16(val);
        else
          reinterpret_cast<float*>(outv)[oo] = val;
      }
    }
  }
}

// ---------------- lm_head GEMM: 256x256 tile, 8 waves, BK=32, 4-buffer pipeline --
// R6 body (best measured: 174 us; VGPR 92, 1 block/CU — do NOT raise min-waves,
// R10 showed launch_bounds(512,4) caps VGPR at 128 and spills acc to scratch).
// 2 sub-phases per K-tile, stage distance 3, per-tile counted vmcnt(8).
// Chunk-XOR swizzle: 0 bank conflicts (measured R5-R11).
#define MM16(ABASE, AF, BF)                                                     \
  _Pragma("unroll") for (int i_ = 0; i_ < 4; ++i_)                              \
      _Pragma("unroll") for (int j_ = 0; j_ < 4; ++j_)                          \
          acc[(ABASE) + i_][j_] = __builtin_amdgcn_mfma_f32_16x16x32_bf16(      \
              (AF)[i_], (BF)[j_], acc[(ABASE) + i_][j_], 0, 0, 0);

__global__ __launch_bounds__(512, 2) void gemm_lmhead(const hb* __restrict__ A,
                                                      const hb* __restrict__ Bw,
                                                      float* __restrict__ out) {
  constexpr int K = 1024, N = 32000, NT = K / 32;  // 32 K-tiles
  __shared__ __align__(16) hb As[4][256][32];
  __shared__ __align__(16) hb Bs[4][256][32];
  const int tid = threadIdx.x, lane = tid & 63, wid = tid >> 6;
  const int nwg = gridDim.x;
  const int dd = blockIdx.x;
  const int wg = (dd & 7) * (nwg >> 3) + (dd >> 3);  // chunked XCD swizzle
  const int m0 = (wg & 7) * 256;
  const int n0 = (wg >> 3) * 256;
  const int wr = wid >> 2, wc = wid & 3;
  const int lr = lane & 15;
  const int rc8 = (((lane >> 4) ^ ((lr >> 1) & 3)) & 3) * 8;  // swizzled read chunk

  f32x4 acc[8][4];
  const f32x4 z = {0.f, 0.f, 0.f, 0.f};
#pragma unroll
  for (int i = 0; i < 8; ++i)
#pragma unroll
    for (int j = 0; j < 4; ++j) acc[i][j] = z;

  const int rr = tid >> 2;
  const int cs = tid & 3;
  const int cc = cs ^ ((tid >> 3) & 3);

  auto stageA = [&](int b, int t) {
#pragma unroll
    for (int q = 0; q < 2; ++q) {
      const int row = q * 128 + rr;
      __builtin_amdgcn_global_load_lds(
          (gptr_t)(A + (size_t)(m0 + row) * K + t * 32 + cc * 8),
          (lptr_t)(&As[b][row][cs * 8]), 16, 0, 0);
    }
  };
  auto stageB = [&](int b, int t) {
#pragma unroll
    for (int q = 0; q < 2; ++q) {
      const int row = q * 128 + rr;
      __builtin_amdgcn_global_load_lds(
          (gptr_t)(Bw + (size_t)(n0 + row) * K + t * 32 + cc * 8),
          (lptr_t)(&Bs[b][row][cs * 8]), 16, 0, 0);
    }
  };
  auto dsA = [&](int b, int mh, bf16x8* af) {
#pragma unroll
    for (int i = 0; i < 4; ++i)
      af[i] = *reinterpret_cast<const bf16x8*>(
          &As[b][wr * 128 + mh * 64 + i * 16 + lr][rc8]);
  };
  auto dsB = [&](int b, bf16x8* bf) {
#pragma unroll
    for (int j = 0; j < 4; ++j)
      bf[j] = *reinterpret_cast<const bf16x8*>(&Bs[b][wc * 64 + j * 16 + lr][rc8]);
  };

  // R6 2-sub-phase tile body; vm = vmcnt immediate (-1 = none); stg = stage t+3
  auto tile = [&](int t, bool stg, int vm) {
    const int c = t & 3;
    const int b3 = (t + 3) & 3;
    bf16x8 af[4], bf[4];
    // Phase A (mh=0): 8 ds_read + stage A-unit
    dsA(c, 0, af);
    dsB(c, bf);
    if (stg) stageA(b3, t + 3);
    __builtin_amdgcn_s_barrier();
    asm volatile("s_waitcnt lgkmcnt(0)" ::: "memory");
    __builtin_amdgcn_s_setprio(1);
    MM16(0, af, bf)
    __builtin_amdgcn_s_setprio(0);
    __builtin_amdgcn_s_barrier();
    // Phase B (mh=1): 4 ds_read + stage B-unit + per-tile vmcnt
    dsA(c, 1, af);
    if (stg) stageB(b3, t + 3);
    if (vm == 8)
      asm volatile("s_waitcnt vmcnt(8)" ::: "memory");
    else if (vm == 4)
      asm volatile("s_waitcnt vmcnt(4)" ::: "memory");
    else if (vm == 0)
      asm volatile("s_waitcnt vmcnt(0)" ::: "memory");
    __builtin_amdgcn_s_barrier();
    asm volatile("s_waitcnt lgkmcnt(0)" ::: "memory");
    __builtin_amdgcn_s_setprio(1);
    MM16(4, af, bf)
    __builtin_amdgcn_s_setprio(0);
    __builtin_amdgcn_s_barrier();
  };

  // prologue: stage tiles 0,1,2 (12 loads); retire tile 0's 4 -> vmcnt(8)
  stageA(0, 0); stageB(0, 0);
  stageA(1, 1); stageB(1, 1);
  stageA(2, 2); stageB(2, 2);
  asm volatile("s_waitcnt vmcnt(8)" ::: "memory");
  __builtin_amdgcn_s_barrier();

  for (int t = 0; t < NT - 3; ++t) tile(t, true, 8);
  tile(NT - 3, false, 4);
  tile(NT - 2, false, 0);
  tile(NT - 1, false, -1);

  // epilogue
  const int lc = lane & 15, lr4 = (lane >> 4) * 4;
#pragma unroll
  for (int i2 = 0; i2 < 8; ++i2) {
    const int grow0 = m0 + wr * 128 + i2 * 16 + lr4;
#pragma unroll
    for (int j = 0; j < 4; ++j) {
      const int gcol = n0 + wc * 64 + j * 16 + lc;
#pragma unroll
      for (int r = 0; r < 4; ++r)
        out[(size_t)(grow0 + r) * N + gcol] = acc[i2][j][r];
    }
  }
}

// ---------------- host ----------------
extern "C" void kernel_launch(void* const* d_in, const int* in_sizes, int n_in,
                              void* d_out, int out_size, void* d_ws, size_t ws_size,
                              hipStream_t stream) {
  const int* idx = (const int*)d_in[0];
  const float* wte = (const float*)d_in[1];
  const float* wpe = (const float*)d_in[2];
  const float* ln1_w = (const float*)d_in[3];
  const float* ln1_b = (const float*)d_in[4];
  const float* qkv_w = (const float*)d_in[5];
  const float* qkv_b = (const float*)d_in[6];
  const float* proj_w = (const float*)d_in[7];
  const float* proj_b = (const float*)d_in[8];
  const float* ln2_w = (const float*)d_in[9];
  const float* ln2_b = (const float*)d_in[10];
  const float* fc1_w = (const float*)d_in[11];
  const float* fc1_b = (const float*)d_in[12];
  const float* fc2_w = (const float*)d_in[13];
  const float* fc2_b = (const float*)d_in[14];
  const float* lnf_w = (const float*)d_in[15];
  const float* lnf_b = (const float*)d_in[16];

  char* ws = (char*)d_ws;
  size_t off = 0;
  auto alloc = [&](size_t bytes) -> void* {
    void* p = ws + off;
    off += (bytes + 255) & ~(size_t)255;
    return p;
  };
  hb* wte_bf = (hb*)alloc((size_t)V_ * D_ * 2);
  hb* qkvw_bf = (hb*)alloc((size_t)L_ * 3 * D_ * D_ * 2);
  hb* projw_bf = (hb*)alloc((size_t)L_ * D_ * D_ * 2);
  hb* fc1w_bf = (hb*)alloc((size_t)L_ * DFF_ * D_ * 2);
  hb* fc2w_bf = (hb*)alloc((size_t)L_ * D_ * DFF_ * 2);
  float* x = (float*)alloc((size_t)BT * D_ * 4);
  hb* hbuf = (hb*)alloc((size_t)BT * D_ * 2);
  hb* qkvbuf = (hb*)alloc((size_t)BT * 3 * D_ * 2);
  hb* ybuf = (hb*)alloc((size_t)BT * D_ * 2);
  hb* gbuf = (hb*)alloc((size_t)BT * DFF_ * 2);
  hb* vtbuf = (hb*)alloc((size_t)B_ * H_ * HD_ * T_ * 2);

  auto cast = [&](const float* src, hb* dst, size_t n) {
    int n4 = (int)(n / 4);
    int blocks = (n4 + 255) / 256;
    if (blocks > 4096) blocks = 4096;
    k_cast_bf16<<<blocks, 256, 0, stream>>>(src, dst, n4);
  };
  cast(wte, wte_bf, (size_t)V_ * D_);
  cast(qkv_w, qkvw_bf, (size_t)L_ * 3 * D_ * D_);
  cast(proj_w, projw_bf, (size_t)L_ * D_ * D_);
  cast(fc1_w, fc1w_bf, (size_t)L_ * DFF_ * D_);
  cast(fc2_w, fc2w_bf, (size_t)L_ * D_ * DFF_);

  k_embed<<<BT * D_ / 256, 256, 0, stream>>>(idx, wte, wpe, x);

  for (int l = 0; l < L_; ++l) {
    k_ln<<<BT, 256, 0, stream>>>(x, ln1_w + l * D_, ln1_b + l * D_, hbuf);
    gemm_bt<0, true, 128><<<MTILES * (3 * D_ / 128), 256, 0, stream>>>(
        hbuf, qkvw_bf + (size_t)l * 3 * D_ * D_, qkv_b + (size_t)l * 3 * D_, nullptr,
        qkvbuf, BT, 3 * D_, D_);
    k_vtrans<<<dim3(B_ * H_, T_ / 64), 256, 0, stream>>>(qkvbuf, vtbuf);
    k_attn<<<(B_ * H_ * (T_ / 16)) / 4, 256, 0, stream>>>(qkvbuf, vtbuf, ybuf);
    gemm_bt<1, false, 64><<<MTILES * (D_ / 64), 256, 0, stream>>>(
        ybuf, projw_bf + (size_t)l * D_ * D_, proj_b + (size_t)l * D_, x, x, BT, D_, D_);
    k_ln<<<BT, 256, 0, stream>>>(x, ln2_w + l * D_, ln2_b + l * D_, hbuf);
    gemm_bt<2, true, 128><<<MTILES * (DFF_ / 128), 256, 0, stream>>>(
        hbuf, fc1w_bf + (size_t)l * DFF_ * D_, fc1_b + (size_t)l * DFF_, nullptr,
        gbuf, BT, DFF_, D_);
    gemm_bt<1, false, 64><<<MTILES * (D_ / 64), 256, 0, stream>>>(
        gbuf, fc2w_bf + (size_t)l * D_ * DFF_, fc2_b + (size_t)l * D_, x, x, BT, D_, DFF_);
  }

  k_ln<<<BT, 256, 0, stream>>>(x, lnf_w, lnf_b, hbuf);
  gemm_lmhead<<<8 * (V_ / 256), 512, 0, stream>>>(hbuf, wte_bf, (float*)d_out);
}